// Round 4
// baseline (559.586 us; speedup 1.0000x reference)
//
#include <hip/hip_runtime.h>
#include <math.h>
#include <stdint.h>

typedef unsigned short u16;
typedef unsigned int u32;
typedef __attribute__((ext_vector_type(8))) short bf16x8;   // 8 bf16 (4 VGPRs)
typedef __attribute__((ext_vector_type(4))) float f32x4;    // MFMA C/D

#define T_TOK 16384
#define NEXP 8
#define HROWS 33792   // 32768 + 8*128  (worst-case padded rows)
#define ROWT 264      // HROWS/128 row tiles

__device__ __forceinline__ u16 f2bf(float f) {
    union { float f; unsigned u; } v; v.f = f;
    unsigned u = v.u;
    return (u16)((u + 0x7fffu + ((u >> 16) & 1u)) >> 16);   // RNE
}

// exact-GELU via Abramowitz-Stegun 7.1.26 erf (max abs err 1.5e-7 << bf16 ulp)
__device__ __forceinline__ float gelu_exact(float h) {
    float x  = h * 0.70710678118654752f;
    float ax = fabsf(x);
    float t  = __builtin_amdgcn_rcpf(1.f + 0.3275911f * ax);
    float p  = t * (0.254829592f + t * (-0.284496736f + t * (1.421413741f +
               t * (-1.453152027f + t * 1.061405429f))));
    float er = 1.f - p * __expf(-x * x);
    er = (x < 0.f) ? -er : er;
    return 0.5f * h * (1.f + er);
}

// async global->LDS, 16B per lane. LDS dest must be wave-uniform base + lane*16.
__device__ __forceinline__ void gload16(const void* g, void* l) {
    __builtin_amdgcn_global_load_lds(
        (const __attribute__((address_space(1))) u32*)(unsigned long long)(uintptr_t)g,
        (__attribute__((address_space(3))) u32*)(unsigned int)(uintptr_t)l,
        16, 0, 0);
}

__device__ __forceinline__ double shfl_xor_dbl(double v, int m) {
    union { double d; int i[2]; } u; u.d = v;
    u.i[0] = __shfl_xor(u.i[0], m, 64);
    u.i[1] = __shfl_xor(u.i[1], m, 64);
    return u.d;
}

// ---- both weight transposes in one launch: [Z][R][C] f32 -> [Z][C][R] bf16 ----
// ids 0..3071: W1 (R=512,C=768); 3072..6143: W2 (R=768,C=512)
__global__ void transpose_all_kernel(const float* __restrict__ W1, const float* __restrict__ W2,
                                     u16* __restrict__ W1t, u16* __restrict__ W2t) {
    __shared__ float tile[32][33];
    int id = blockIdx.x;
    const float* src; u16* dst; int R, C, e, c0, r0;
    if (id < 3072) {
        R = 512; C = 768; e = id / 384; int rem = id % 384;
        c0 = (rem % 24) * 32; r0 = (rem / 24) * 32;
        src = W1; dst = W1t;
    } else {
        id -= 3072;
        R = 768; C = 512; e = id / 384; int rem = id % 384;
        c0 = (rem % 16) * 32; r0 = (rem / 16) * 32;
        src = W2; dst = W2t;
    }
    int tx = threadIdx.x & 31, ty = threadIdx.x >> 5;   // ty in 0..7
    const float* s = src + (size_t)e * R * C;
#pragma unroll
    for (int i = 0; i < 32; i += 8)
        tile[ty + i][tx] = s[(size_t)(r0 + ty + i) * C + (c0 + tx)];
    __syncthreads();
    u16* d = dst + (size_t)e * R * C;
#pragma unroll
    for (int i = 0; i < 32; i += 8)
        d[(size_t)(c0 + ty + i) * R + (r0 + tx)] = f2bf(tile[tx][ty + i]);
}

// ------ router: fp64 scores, 8-way K split, top-2 gates, lists; also emits xb (bf16 x) ------
// 512 blocks x 256 threads (4 waves). Wave: 8 tokens x 8 k-chunks (64 k each).
// Wg staged as fp64 in LDS, bank-skewed: slot(j,k) = (j + (k>>3) + (k>>6)) & 7
// so the 8 kh-groups of a wave hit 8 distinct banks (unskewed: all hit bank 0).
__global__ __launch_bounds__(256) void router_kernel(
    const float* __restrict__ x, const float* __restrict__ Wg,
    const float* __restrict__ bg, int* __restrict__ counts,
    int* __restrict__ tokenlist, float* __restrict__ gatelist,
    u16* __restrict__ xb) {
    __shared__ double wgd[4096];
    int tid = threadIdx.x;
    for (int i = tid; i < 4096; i += 256) {
        int k = i >> 3, j = i & 7;
        int slot = (j + (k >> 3) + (k >> 6)) & 7;
        wgd[k * 8 + slot] = (double)Wg[i];
    }
    __syncthreads();

    int w = tid >> 6, lane = tid & 63;
    int kh = lane >> 3, tl = lane & 7;
    int t  = blockIdx.x * 32 + w * 8 + tl;
    int k0 = kh * 64;
    const float* xr = x  + (size_t)t * 512 + k0;
    u16*       xrow = xb + (size_t)t * 512 + k0;

    double acc[8];
#pragma unroll
    for (int j = 0; j < 8; j++) acc[j] = 0.0;
    for (int kc = 0; kc < 64; kc += 4) {
        float4 v = *(const float4*)(xr + kc);
        ushort4 o;
        o.x = f2bf(v.x); o.y = f2bf(v.y); o.z = f2bf(v.z); o.w = f2bf(v.w);
        *(ushort4*)(xrow + kc) = o;
        float vv[4] = { v.x, v.y, v.z, v.w };
#pragma unroll
        for (int q = 0; q < 4; q++) {
            int kl = kc + q;
            double dv = (double)vv[q];
            const double* wr = wgd + (size_t)(k0 + kl) * 8;
            int sk = (kl >> 3) + kh;
#pragma unroll
            for (int j = 0; j < 8; j++)
                acc[j] += dv * wr[(j + sk) & 7];
        }
    }
#pragma unroll
    for (int j = 0; j < 8; j++) {
        acc[j] += shfl_xor_dbl(acc[j], 8);
        acc[j] += shfl_xor_dbl(acc[j], 16);
        acc[j] += shfl_xor_dbl(acc[j], 32);
    }

    double s[8];
#pragma unroll
    for (int j = 0; j < 8; j++) s[j] = acc[j] + (double)bg[j];
    int i0 = 0;
#pragma unroll
    for (int j = 1; j < 8; j++) if (s[j] > s[i0]) i0 = j;
    int i1 = (i0 == 0) ? 1 : 0;
#pragma unroll
    for (int j = 0; j < 8; j++) if (j != i0 && s[j] > s[i1]) i1 = j;
    float d  = expf((float)(s[i1] - s[i0]));
    float g0 = 1.f / (1.f + d);
    float g1 = d / (1.f + d);

    unsigned long long lt = (1ull << lane) - 1ull;
    for (int j = 0; j < NEXP; j++) {
#pragma unroll
        for (int p = 0; p < 2; p++) {
            int   ej = p ? i1 : i0;
            float gj = p ? g1 : g0;
            unsigned long long m = __ballot(kh == 0 && ej == j);
            if (m) {
                int leader = __ffsll(m) - 1;
                int base = 0;
                if (lane == leader) base = atomicAdd(&counts[j], __popcll(m));
                base = __shfl(base, leader);
                if (kh == 0 && ej == j) {
                    int slot = base + __popcll(m & lt);
                    tokenlist[j * T_TOK + slot] = t;
                    gatelist [j * T_TOK + slot] = gj;
                }
            }
        }
    }
}

// ---------------- m97-style 128x128 GEMM, BK=64, 4 waves, global_load_lds staging ----------------
// PASS1: C = gathered xb @ W1t  -> GELU -> H (bf16, coalesced via LDS bounce)
// PASS2: C = H @ W2t -> (+b2)*gate -> atomicAdd scatter into out
template<int PASS>
__global__ __launch_bounds__(256) void moe_gemm(
    const u16* __restrict__ A, const u16* __restrict__ W,
    const float* __restrict__ bias,
    const int* __restrict__ counts,
    const int* __restrict__ tokenlist, const float* __restrict__ gatelist,
    u16* __restrict__ Hout, float* __restrict__ out)
{
    constexpr int N = (PASS == 1) ? 768 : 512;
    constexpr int K = (PASS == 1) ? 512 : 768;

    __shared__ __align__(16) char smem[32768];   // As(16K)+Bs(16K); reused as epilogue bounce
    __shared__ int   tokrow[128];
    __shared__ float gaterow[128];
    __shared__ int   spo[9];

    int tid = threadIdx.x;
    int rt  = blockIdx.x % ROWT;      // adjacent blocks share the B panel
    int ct  = blockIdx.x / ROWT;
    int row0 = rt * 128;

    if (tid == 0) {
        int s = 0;
#pragma unroll
        for (int e = 0; e < NEXP; e++) { spo[e] = s; s += (counts[e] + 127) & ~127; }
        spo[NEXP] = s;
    }
    __syncthreads();
    if (row0 >= spo[8]) return;
    int e = 0;
    while (row0 >= spo[e + 1]) e++;
    int lr0 = row0 - spo[e];
    int cnt = counts[e];
    if (tid < 128) {
        int slot = lr0 + tid;
        int cl   = slot < cnt ? slot : cnt - 1;
        tokrow[tid]  = tokenlist[e * T_TOK + cl];
        gaterow[tid] = gatelist[e * T_TOK + cl];
    }
    __syncthreads();

    int n0 = ct * 128;
    char* As = smem;
    char* Bs = smem + 16384;

    // staging source pointers: dest chunk (iss*256+tid) is linear; source column is
    // XOR-swizzled so that swizzled LDS reads below see the un-swizzled element.
    const u16* aptr[4];
    const u16* bptr[4];
    const u16* wbase = W + (size_t)e * ((size_t)N * K);
#pragma unroll
    for (int iss = 0; iss < 4; iss++) {
        int chunk = iss * 256 + tid;
        int row   = chunk >> 3;
        int c16   = (chunk & 7) ^ (row & 7);
        if (PASS == 1)
            aptr[iss] = A + (size_t)tokrow[row] * K + c16 * 8;
        else
            aptr[iss] = A + (size_t)(row0 + row) * K + c16 * 8;
        bptr[iss] = wbase + (size_t)(n0 + row) * K + c16 * 8;
    }

    int lane = tid & 63, w = tid >> 6;
    int wr = w >> 1, wc = w & 1;                  // 2x2 waves, 64x64 each
    int lr = lane & 15, hk = lane >> 4;

    f32x4 acc[4][4];
#pragma unroll
    for (int mi = 0; mi < 4; mi++)
#pragma unroll
        for (int ni = 0; ni < 4; ni++)
            acc[mi][ni] = (f32x4){0.f, 0.f, 0.f, 0.f};

    for (int kk = 0; kk < K; kk += 64) {
#pragma unroll
        for (int iss = 0; iss < 4; iss++) {
            gload16(aptr[iss] + kk, As + (iss * 256 + tid) * 16);
            gload16(bptr[iss] + kk, Bs + (iss * 256 + tid) * 16);
        }
        __syncthreads();
#pragma unroll
        for (int ks = 0; ks < 2; ks++) {
            bf16x8 af[4], bfr[4];
#pragma unroll
            for (int mi = 0; mi < 4; mi++) {
                int row = wr * 64 + mi * 16 + lr;
                af[mi] = *(const bf16x8*)(As + row * 128 + (((ks * 4 + hk) ^ (row & 7)) * 16));
            }
#pragma unroll
            for (int ni = 0; ni < 4; ni++) {
                int row = wc * 64 + ni * 16 + lr;
                bfr[ni] = *(const bf16x8*)(Bs + row * 128 + (((ks * 4 + hk) ^ (row & 7)) * 16));
            }
#pragma unroll
            for (int mi = 0; mi < 4; mi++)
#pragma unroll
                for (int ni = 0; ni < 4; ni++)
                    acc[mi][ni] = __builtin_amdgcn_mfma_f32_16x16x32_bf16(
                        af[mi], bfr[ni], acc[mi][ni], 0, 0, 0);
        }
        __syncthreads();
    }

    if (PASS == 1) {
        // bias + exact GELU -> LDS bounce (bf16 [128][128] = 128 rows x 256B) -> coalesced stores
#pragma unroll
        for (int ni = 0; ni < 4; ni++) {
            int lcol = wc * 64 + ni * 16 + lr;
            float bb = bias[e * N + n0 + lcol];
#pragma unroll
            for (int mi = 0; mi < 4; mi++) {
#pragma unroll
                for (int r = 0; r < 4; r++) {
                    int row = wr * 64 + mi * 16 + hk * 4 + r;
                    *(u16*)(smem + row * 256 + lcol * 2) = f2bf(gelu_exact(acc[mi][ni][r] + bb));
                }
            }
        }
        __syncthreads();
        // 2048 chunks of 16B: 16 chunks per row (256B), 128 rows
#pragma unroll
        for (int iss = 0; iss < 8; iss++) {
            int chunk = iss * 256 + tid;
            int row = chunk >> 4, c16 = chunk & 15;
            uint4 v = *(const uint4*)(smem + row * 256 + c16 * 16);
            *(uint4*)(Hout + (size_t)(row0 + row) * 768 + n0 + c16 * 8) = v;
        }
    } else {
        // (+b2) * gate -> atomic scatter
#pragma unroll
        for (int ni = 0; ni < 4; ni++) {
            int gcol = n0 + wc * 64 + ni * 16 + lr;
            float bb = bias[e * N + gcol];
#pragma unroll
            for (int mi = 0; mi < 4; mi++) {
#pragma unroll
                for (int r = 0; r < 4; r++) {
                    int row  = wr * 64 + mi * 16 + hk * 4 + r;
                    int slot = lr0 + row;
                    if (slot < cnt) {
                        int   tok = tokrow[row];
                        float g   = gaterow[row];
                        atomicAdd(out + (size_t)tok * 512 + gcol,
                                  (acc[mi][ni][r] + bb) * g);
                    }
                }
            }
        }
    }
}

extern "C" void kernel_launch(void* const* d_in, const int* in_sizes, int n_in,
                              void* d_out, int out_size, void* d_ws, size_t ws_size,
                              hipStream_t stream) {
    const float* x  = (const float*)d_in[0];   // [8,2048,512]
    const float* Wg = (const float*)d_in[1];   // [512,8]
    const float* bg = (const float*)d_in[2];   // [8]
    const float* W1 = (const float*)d_in[3];   // [8,512,768]
    const float* b1 = (const float*)d_in[4];   // [8,768]
    const float* W2 = (const float*)d_in[5];   // [8,768,512]
    const float* b2 = (const float*)d_in[6];   // [8,512]
    float* out = (float*)d_out;                // [8,2048,512] fp32

    char* ws = (char*)d_ws;
    int*   counts    = (int*)(ws + 0);                    // 8 ints
    int*   tokenlist = (int*)(ws + 1024);                 // 8*16384 int   (512 KB)
    float* gatelist  = (float*)(ws + 526336);             // 8*16384 f32   (512 KB)
    u16*   xb        = (u16*)(ws + 1052672);              // 16384*512 bf16 (16 MB)
    u16*   W1t       = (u16*)(ws + 17829888);             // [8][768][512] bf16 (6 MB)
    u16*   W2t       = (u16*)(ws + 24121344);             // [8][512][768] bf16 (6 MB)
    u16*   H         = (u16*)(ws + 30412800);             // [33792][768] bf16 (51.9 MB)
    (void)in_sizes; (void)n_in; (void)ws_size;

    hipMemsetAsync(d_out, 0, (size_t)out_size * sizeof(float), stream);
    hipMemsetAsync(counts, 0, 32, stream);

    router_kernel<<<512, 256, 0, stream>>>(x, Wg, bg, counts, tokenlist, gatelist, xb);
    transpose_all_kernel<<<6144, 256, 0, stream>>>(W1, W2, W1t, W2t);

    moe_gemm<1><<<6 * ROWT, 256, 0, stream>>>(xb, W1t, b1, counts,
                                              tokenlist, gatelist, H, nullptr);
    moe_gemm<2><<<4 * ROWT, 256, 0, stream>>>(H, W2t, b2, counts,
                                              tokenlist, gatelist, nullptr, out);
}

// Round 5
// 541.978 us; speedup vs baseline: 1.0325x; 1.0325x over previous
//
#include <hip/hip_runtime.h>
#include <math.h>
#include <stdint.h>

typedef unsigned short u16;
typedef unsigned int u32;
typedef __attribute__((ext_vector_type(8))) short bf16x8;   // 8 bf16 (4 VGPRs)
typedef __attribute__((ext_vector_type(4))) float f32x4;    // MFMA C/D

#define T_TOK 16384
#define NEXP 8
#define HROWS 33792   // 32768 + 8*128  (worst-case padded rows)
#define ROWT 264      // HROWS/128 row tiles

__device__ __forceinline__ u16 f2bf(float f) {
    union { float f; unsigned u; } v; v.f = f;
    unsigned u = v.u;
    return (u16)((u + 0x7fffu + ((u >> 16) & 1u)) >> 16);   // RNE
}

// exact-GELU via Abramowitz-Stegun 7.1.26 erf (max abs err 1.5e-7 << bf16 ulp)
__device__ __forceinline__ float gelu_exact(float h) {
    float x  = h * 0.70710678118654752f;
    float ax = fabsf(x);
    float t  = __builtin_amdgcn_rcpf(1.f + 0.3275911f * ax);
    float p  = t * (0.254829592f + t * (-0.284496736f + t * (1.421413741f +
               t * (-1.453152027f + t * 1.061405429f))));
    float er = 1.f - p * __expf(-x * x);
    er = (x < 0.f) ? -er : er;
    return 0.5f * h * (1.f + er);
}

// async global->LDS, 16B per lane. LDS dest must be wave-uniform base + lane*16.
__device__ __forceinline__ void gload16(const void* g, void* l) {
    __builtin_amdgcn_global_load_lds(
        (const __attribute__((address_space(1))) u32*)(unsigned long long)(uintptr_t)g,
        (__attribute__((address_space(3))) u32*)(unsigned int)(uintptr_t)l,
        16, 0, 0);
}

__device__ __forceinline__ double shfl_xor_dbl(double v, int m) {
    union { double d; int i[2]; } u; u.d = v;
    u.i[0] = __shfl_xor(u.i[0], m, 64);
    u.i[1] = __shfl_xor(u.i[1], m, 64);
    return u.d;
}

// ---- both weight transposes in one launch: [Z][R][C] f32 -> [Z][C][R] bf16 ----
// ids 0..3071: W1 (R=512,C=768); 3072..6143: W2 (R=768,C=512)
__global__ void transpose_all_kernel(const float* __restrict__ W1, const float* __restrict__ W2,
                                     u16* __restrict__ W1t, u16* __restrict__ W2t) {
    __shared__ float tile[32][33];
    int id = blockIdx.x;
    const float* src; u16* dst; int R, C, e, c0, r0;
    if (id < 3072) {
        R = 512; C = 768; e = id / 384; int rem = id % 384;
        c0 = (rem % 24) * 32; r0 = (rem / 24) * 32;
        src = W1; dst = W1t;
    } else {
        id -= 3072;
        R = 768; C = 512; e = id / 384; int rem = id % 384;
        c0 = (rem % 16) * 32; r0 = (rem / 16) * 32;
        src = W2; dst = W2t;
    }
    int tx = threadIdx.x & 31, ty = threadIdx.x >> 5;   // ty in 0..7
    const float* s = src + (size_t)e * R * C;
#pragma unroll
    for (int i = 0; i < 32; i += 8)
        tile[ty + i][tx] = s[(size_t)(r0 + ty + i) * C + (c0 + tx)];
    __syncthreads();
    u16* d = dst + (size_t)e * R * C;
#pragma unroll
    for (int i = 0; i < 32; i += 8)
        d[(size_t)(c0 + ty + i) * R + (r0 + tx)] = f2bf(tile[tx][ty + i]);
}

// ------ router: fp64 scores, top-2 gates, lists; also emits xb (bf16 x) ------
// 512 blocks x 256 threads (4 waves). Wave: 8 token groups of 8 CONSECUTIVE lanes.
// tg = lane>>3 (token), sl = lane&7 (k-split). Lane's float4 #it at byte
// t*2048 + it*128 + sl*16 -> per instruction: 8 contiguous fully-used 128B
// segments on 8 consecutive token rows (zero over-fetch; round-4's scatter fixed).
// Wg in LDS as f64, rotation-skewed: store wgd[k*8 + (j + ((k>>2)&7))&7]; for this
// k-pattern ((k>>2)&7) == sl, so reader rotation = (j+sl)&7 -> 8 distinct bank
// pairs per instruction across sl, broadcast across token groups: conflict-free.
__global__ __launch_bounds__(256) void router_kernel(
    const float* __restrict__ x, const float* __restrict__ Wg,
    const float* __restrict__ bg, int* __restrict__ counts,
    int* __restrict__ tokenlist, float* __restrict__ gatelist,
    u16* __restrict__ xb) {
    __shared__ double wgd[4096];
    int tid = threadIdx.x;
    for (int i = tid; i < 4096; i += 256) {
        int k = i >> 3, j = i & 7;
        int slot = (j + ((k >> 2) & 7)) & 7;
        wgd[k * 8 + slot] = (double)Wg[i];
    }
    __syncthreads();

    int w = tid >> 6, lane = tid & 63;
    int tg = lane >> 3, sl = lane & 7;
    int t  = blockIdx.x * 32 + w * 8 + tg;
    const float* xr = x  + (size_t)t * 512;
    u16*       xrow = xb + (size_t)t * 512;

    // stage all 16 float4 loads (max memory-level parallelism)
    float4 xv[16];
#pragma unroll
    for (int it = 0; it < 16; it++)
        xv[it] = *(const float4*)(xr + it * 32 + sl * 4);

    // bf16 conversion + coalesced store (same pattern as loads)
#pragma unroll
    for (int it = 0; it < 16; it++) {
        ushort4 o;
        o.x = f2bf(xv[it].x); o.y = f2bf(xv[it].y);
        o.z = f2bf(xv[it].z); o.w = f2bf(xv[it].w);
        *(ushort4*)(xrow + it * 32 + sl * 4) = o;
    }

    // precompute rotated j-slots (zero per-read cost)
    int jr[8];
#pragma unroll
    for (int j = 0; j < 8; j++) jr[j] = (j + sl) & 7;

    double acc[8];
#pragma unroll
    for (int j = 0; j < 8; j++) acc[j] = 0.0;
#pragma unroll
    for (int it = 0; it < 16; it++) {
        float vv[4] = { xv[it].x, xv[it].y, xv[it].z, xv[it].w };
#pragma unroll
        for (int q = 0; q < 4; q++) {
            int k = it * 32 + sl * 4 + q;
            double dv = (double)vv[q];
            const double* wr = wgd + (size_t)k * 8;
#pragma unroll
            for (int j = 0; j < 8; j++)
                acc[j] += dv * wr[jr[j]];
        }
    }
    // reduce across the 8 consecutive lanes of the token group
#pragma unroll
    for (int j = 0; j < 8; j++) {
        acc[j] += shfl_xor_dbl(acc[j], 1);
        acc[j] += shfl_xor_dbl(acc[j], 2);
        acc[j] += shfl_xor_dbl(acc[j], 4);
    }

    double s[8];
#pragma unroll
    for (int j = 0; j < 8; j++) s[j] = acc[j] + (double)bg[j];
    int i0 = 0;
#pragma unroll
    for (int j = 1; j < 8; j++) if (s[j] > s[i0]) i0 = j;
    int i1 = (i0 == 0) ? 1 : 0;
#pragma unroll
    for (int j = 0; j < 8; j++) if (j != i0 && s[j] > s[i1]) i1 = j;
    float d  = expf((float)(s[i1] - s[i0]));
    float g0 = 1.f / (1.f + d);
    float g1 = d / (1.f + d);

    int act = (sl == 0);
    unsigned long long lt = (1ull << lane) - 1ull;
    for (int j = 0; j < NEXP; j++) {
#pragma unroll
        for (int p = 0; p < 2; p++) {
            int   ej = p ? i1 : i0;
            float gj = p ? g1 : g0;
            unsigned long long m = __ballot(act && ej == j);
            if (m) {
                int leader = __ffsll(m) - 1;
                int base = 0;
                if (lane == leader) base = atomicAdd(&counts[j], __popcll(m));
                base = __shfl(base, leader);
                if (act && ej == j) {
                    int slot = base + __popcll(m & lt);
                    tokenlist[j * T_TOK + slot] = t;
                    gatelist [j * T_TOK + slot] = gj;
                }
            }
        }
    }
}

// ---------------- m97-style 128x128 GEMM, BK=64, 4 waves, global_load_lds staging ----------------
// PASS1: C = gathered xb @ W1t  -> GELU -> H (bf16, coalesced via LDS bounce)
// PASS2: C = H @ W2t -> (+b2)*gate -> atomicAdd scatter into out
template<int PASS>
__global__ __launch_bounds__(256) void moe_gemm(
    const u16* __restrict__ A, const u16* __restrict__ W,
    const float* __restrict__ bias,
    const int* __restrict__ counts,
    const int* __restrict__ tokenlist, const float* __restrict__ gatelist,
    u16* __restrict__ Hout, float* __restrict__ out)
{
    constexpr int N = (PASS == 1) ? 768 : 512;
    constexpr int K = (PASS == 1) ? 512 : 768;

    __shared__ __align__(16) char smem[32768];   // As(16K)+Bs(16K); reused as epilogue bounce
    __shared__ int   tokrow[128];
    __shared__ float gaterow[128];
    __shared__ int   spo[9];

    int tid = threadIdx.x;
    int rt  = blockIdx.x % ROWT;      // adjacent blocks share the B panel
    int ct  = blockIdx.x / ROWT;
    int row0 = rt * 128;

    if (tid == 0) {
        int s = 0;
#pragma unroll
        for (int e = 0; e < NEXP; e++) { spo[e] = s; s += (counts[e] + 127) & ~127; }
        spo[NEXP] = s;
    }
    __syncthreads();
    if (row0 >= spo[8]) return;
    int e = 0;
    while (row0 >= spo[e + 1]) e++;
    int lr0 = row0 - spo[e];
    int cnt = counts[e];
    if (tid < 128) {
        int slot = lr0 + tid;
        int cl   = slot < cnt ? slot : cnt - 1;
        tokrow[tid]  = tokenlist[e * T_TOK + cl];
        gaterow[tid] = gatelist[e * T_TOK + cl];
    }
    __syncthreads();

    int n0 = ct * 128;
    char* As = smem;
    char* Bs = smem + 16384;

    // staging source pointers: dest chunk (iss*256+tid) is linear; source column is
    // XOR-swizzled so that swizzled LDS reads below see the un-swizzled element.
    const u16* aptr[4];
    const u16* bptr[4];
    const u16* wbase = W + (size_t)e * ((size_t)N * K);
#pragma unroll
    for (int iss = 0; iss < 4; iss++) {
        int chunk = iss * 256 + tid;
        int row   = chunk >> 3;
        int c16   = (chunk & 7) ^ (row & 7);
        if (PASS == 1)
            aptr[iss] = A + (size_t)tokrow[row] * K + c16 * 8;
        else
            aptr[iss] = A + (size_t)(row0 + row) * K + c16 * 8;
        bptr[iss] = wbase + (size_t)(n0 + row) * K + c16 * 8;
    }

    int lane = tid & 63, w = tid >> 6;
    int wr = w >> 1, wc = w & 1;                  // 2x2 waves, 64x64 each
    int lr = lane & 15, hk = lane >> 4;

    f32x4 acc[4][4];
#pragma unroll
    for (int mi = 0; mi < 4; mi++)
#pragma unroll
        for (int ni = 0; ni < 4; ni++)
            acc[mi][ni] = (f32x4){0.f, 0.f, 0.f, 0.f};

    for (int kk = 0; kk < K; kk += 64) {
#pragma unroll
        for (int iss = 0; iss < 4; iss++) {
            gload16(aptr[iss] + kk, As + (iss * 256 + tid) * 16);
            gload16(bptr[iss] + kk, Bs + (iss * 256 + tid) * 16);
        }
        __syncthreads();
#pragma unroll
        for (int ks = 0; ks < 2; ks++) {
            bf16x8 af[4], bfr[4];
#pragma unroll
            for (int mi = 0; mi < 4; mi++) {
                int row = wr * 64 + mi * 16 + lr;
                af[mi] = *(const bf16x8*)(As + row * 128 + (((ks * 4 + hk) ^ (row & 7)) * 16));
            }
#pragma unroll
            for (int ni = 0; ni < 4; ni++) {
                int row = wc * 64 + ni * 16 + lr;
                bfr[ni] = *(const bf16x8*)(Bs + row * 128 + (((ks * 4 + hk) ^ (row & 7)) * 16));
            }
#pragma unroll
            for (int mi = 0; mi < 4; mi++)
#pragma unroll
                for (int ni = 0; ni < 4; ni++)
                    acc[mi][ni] = __builtin_amdgcn_mfma_f32_16x16x32_bf16(
                        af[mi], bfr[ni], acc[mi][ni], 0, 0, 0);
        }
        __syncthreads();
    }

    if (PASS == 1) {
        // bias + exact GELU -> LDS bounce (bf16 [128][128] = 128 rows x 256B) -> coalesced stores
#pragma unroll
        for (int ni = 0; ni < 4; ni++) {
            int lcol = wc * 64 + ni * 16 + lr;
            float bb = bias[e * N + n0 + lcol];
#pragma unroll
            for (int mi = 0; mi < 4; mi++) {
#pragma unroll
                for (int r = 0; r < 4; r++) {
                    int row = wr * 64 + mi * 16 + hk * 4 + r;
                    *(u16*)(smem + row * 256 + lcol * 2) = f2bf(gelu_exact(acc[mi][ni][r] + bb));
                }
            }
        }
        __syncthreads();
        // 2048 chunks of 16B: 16 chunks per row (256B), 128 rows
#pragma unroll
        for (int iss = 0; iss < 8; iss++) {
            int chunk = iss * 256 + tid;
            int row = chunk >> 4, c16 = chunk & 15;
            uint4 v = *(const uint4*)(smem + row * 256 + c16 * 16);
            *(uint4*)(Hout + (size_t)(row0 + row) * 768 + n0 + c16 * 8) = v;
        }
    } else {
        // (+b2) * gate -> atomic scatter
#pragma unroll
        for (int ni = 0; ni < 4; ni++) {
            int gcol = n0 + wc * 64 + ni * 16 + lr;
            float bb = bias[e * N + gcol];
#pragma unroll
            for (int mi = 0; mi < 4; mi++) {
#pragma unroll
                for (int r = 0; r < 4; r++) {
                    int row  = wr * 64 + mi * 16 + hk * 4 + r;
                    int slot = lr0 + row;
                    if (slot < cnt) {
                        int   tok = tokrow[row];
                        float g   = gaterow[row];
                        atomicAdd(out + (size_t)tok * 512 + gcol,
                                  (acc[mi][ni][r] + bb) * g);
                    }
                }
            }
        }
    }
}

extern "C" void kernel_launch(void* const* d_in, const int* in_sizes, int n_in,
                              void* d_out, int out_size, void* d_ws, size_t ws_size,
                              hipStream_t stream) {
    const float* x  = (const float*)d_in[0];   // [8,2048,512]
    const float* Wg = (const float*)d_in[1];   // [512,8]
    const float* bg = (const float*)d_in[2];   // [8]
    const float* W1 = (const float*)d_in[3];   // [8,512,768]
    const float* b1 = (const float*)d_in[4];   // [8,768]
    const float* W2 = (const float*)d_in[5];   // [8,768,512]
    const float* b2 = (const float*)d_in[6];   // [8,512]
    float* out = (float*)d_out;                // [8,2048,512] fp32

    char* ws = (char*)d_ws;
    int*   counts    = (int*)(ws + 0);                    // 8 ints
    int*   tokenlist = (int*)(ws + 1024);                 // 8*16384 int   (512 KB)
    float* gatelist  = (float*)(ws + 526336);             // 8*16384 f32   (512 KB)
    u16*   xb        = (u16*)(ws + 1052672);              // 16384*512 bf16 (16 MB)
    u16*   W1t       = (u16*)(ws + 17829888);             // [8][768][512] bf16 (6 MB)
    u16*   W2t       = (u16*)(ws + 24121344);             // [8][512][768] bf16 (6 MB)
    u16*   H         = (u16*)(ws + 30412800);             // [33792][768] bf16 (51.9 MB)
    (void)in_sizes; (void)n_in; (void)ws_size;

    hipMemsetAsync(d_out, 0, (size_t)out_size * sizeof(float), stream);
    hipMemsetAsync(counts, 0, 32, stream);

    router_kernel<<<512, 256, 0, stream>>>(x, Wg, bg, counts, tokenlist, gatelist, xb);
    transpose_all_kernel<<<6144, 256, 0, stream>>>(W1, W2, W1t, W2t);

    moe_gemm<1><<<6 * ROWT, 256, 0, stream>>>(xb, W1t, b1, counts,
                                              tokenlist, gatelist, H, nullptr);
    moe_gemm<2><<<4 * ROWT, 256, 0, stream>>>(H, W2t, b2, counts,
                                              tokenlist, gatelist, nullptr, out);
}

// Round 6
// 307.237 us; speedup vs baseline: 1.8213x; 1.7640x over previous
//
#include <hip/hip_runtime.h>
#include <math.h>
#include <stdint.h>

typedef unsigned short u16;
typedef unsigned int u32;
typedef __attribute__((ext_vector_type(8))) short bf16x8;   // 8 bf16 (4 VGPRs)
typedef __attribute__((ext_vector_type(4))) float f32x4;    // MFMA C/D

#define T_TOK 16384
#define NEXP 8
#define HROWS 33792   // 32768 + 8*128  (worst-case padded rows)
#define ROWT 264      // HROWS/128 row tiles

__device__ __forceinline__ u16 f2bf(float f) {
    union { float f; unsigned u; } v; v.f = f;
    unsigned u = v.u;
    return (u16)((u + 0x7fffu + ((u >> 16) & 1u)) >> 16);   // RNE
}

// exact-GELU via Abramowitz-Stegun 7.1.26 erf (max abs err 1.5e-7 << bf16 ulp)
__device__ __forceinline__ float gelu_exact(float h) {
    float x  = h * 0.70710678118654752f;
    float ax = fabsf(x);
    float t  = __builtin_amdgcn_rcpf(1.f + 0.3275911f * ax);
    float p  = t * (0.254829592f + t * (-0.284496736f + t * (1.421413741f +
               t * (-1.453152027f + t * 1.061405429f))));
    float er = 1.f - p * __expf(-x * x);
    er = (x < 0.f) ? -er : er;
    return 0.5f * h * (1.f + er);
}

// async global->LDS, 16B per lane. LDS dest must be wave-uniform base + lane*16.
__device__ __forceinline__ void gload16(const void* g, void* l) {
    __builtin_amdgcn_global_load_lds(
        (const __attribute__((address_space(1))) u32*)(unsigned long long)(uintptr_t)g,
        (__attribute__((address_space(3))) u32*)(unsigned int)(uintptr_t)l,
        16, 0, 0);
}

__device__ __forceinline__ double shfl_xor_dbl(double v, int m) {
    union { double d; int i[2]; } u; u.d = v;
    u.i[0] = __shfl_xor(u.i[0], m, 64);
    u.i[1] = __shfl_xor(u.i[1], m, 64);
    return u.d;
}

// ---- both weight transposes in one launch: [Z][R][C] f32 -> [Z][C][R] bf16 ----
__global__ void transpose_all_kernel(const float* __restrict__ W1, const float* __restrict__ W2,
                                     u16* __restrict__ W1t, u16* __restrict__ W2t) {
    __shared__ float tile[32][33];
    int id = blockIdx.x;
    const float* src; u16* dst; int R, C, e, c0, r0;
    if (id < 3072) {
        R = 512; C = 768; e = id / 384; int rem = id % 384;
        c0 = (rem % 24) * 32; r0 = (rem / 24) * 32;
        src = W1; dst = W1t;
    } else {
        id -= 3072;
        R = 768; C = 512; e = id / 384; int rem = id % 384;
        c0 = (rem % 16) * 32; r0 = (rem / 16) * 32;
        src = W2; dst = W2t;
    }
    int tx = threadIdx.x & 31, ty = threadIdx.x >> 5;
    const float* s = src + (size_t)e * R * C;
#pragma unroll
    for (int i = 0; i < 32; i += 8)
        tile[ty + i][tx] = s[(size_t)(r0 + ty + i) * C + (c0 + tx)];
    __syncthreads();
    u16* d = dst + (size_t)e * R * C;
#pragma unroll
    for (int i = 0; i < 32; i += 8)
        d[(size_t)(c0 + ty + i) * R + (r0 + tx)] = f2bf(tile[tx][ty + i]);
}

// ------ R1: routing math (fp64), emits xb (bf16 x), packed per-token choices, and
// per-block expert counts. ZERO global atomics (round-5's 266us was counts[] atomic
// serialization: ~21K device-scope atomics on one cache line @ ~16ns each).
// 512 blocks x 256 threads. Wave: 8 token groups of 8 consecutive lanes.
// Memory pattern (round-5, verified ideal FETCH): lane float4 #it at t*2048+it*128+sl*16.
__global__ __launch_bounds__(256) void router_kernel(
    const float* __restrict__ x, const float* __restrict__ Wg,
    const float* __restrict__ bg,
    u16* __restrict__ xb, float4* __restrict__ packed, int* __restrict__ blockcnt) {
    __shared__ double wgd[4096];
    __shared__ int lcnt[8];
    int tid = threadIdx.x;
    if (tid < 8) lcnt[tid] = 0;
    for (int i = tid; i < 4096; i += 256) {
        int k = i >> 3, j = i & 7;
        int slot = (j + ((k >> 2) & 7)) & 7;
        wgd[k * 8 + slot] = (double)Wg[i];
    }
    __syncthreads();

    int w = tid >> 6, lane = tid & 63;
    int tg = lane >> 3, sl = lane & 7;
    int t  = blockIdx.x * 32 + w * 8 + tg;
    const float* xr = x  + (size_t)t * 512;
    u16*       xrow = xb + (size_t)t * 512;

    float4 xv[16];
#pragma unroll
    for (int it = 0; it < 16; it++)
        xv[it] = *(const float4*)(xr + it * 32 + sl * 4);

#pragma unroll
    for (int it = 0; it < 16; it++) {
        ushort4 o;
        o.x = f2bf(xv[it].x); o.y = f2bf(xv[it].y);
        o.z = f2bf(xv[it].z); o.w = f2bf(xv[it].w);
        *(ushort4*)(xrow + it * 32 + sl * 4) = o;
    }

    int jr[8];
#pragma unroll
    for (int j = 0; j < 8; j++) jr[j] = (j + sl) & 7;

    double acc[8];
#pragma unroll
    for (int j = 0; j < 8; j++) acc[j] = 0.0;
#pragma unroll
    for (int it = 0; it < 16; it++) {
        float vv[4] = { xv[it].x, xv[it].y, xv[it].z, xv[it].w };
#pragma unroll
        for (int q = 0; q < 4; q++) {
            int k = it * 32 + sl * 4 + q;
            double dv = (double)vv[q];
            const double* wr = wgd + (size_t)k * 8;
#pragma unroll
            for (int j = 0; j < 8; j++)
                acc[j] += dv * wr[jr[j]];
        }
    }
#pragma unroll
    for (int j = 0; j < 8; j++) {
        acc[j] += shfl_xor_dbl(acc[j], 1);
        acc[j] += shfl_xor_dbl(acc[j], 2);
        acc[j] += shfl_xor_dbl(acc[j], 4);
    }

    double s[8];
#pragma unroll
    for (int j = 0; j < 8; j++) s[j] = acc[j] + (double)bg[j];
    int i0 = 0;
#pragma unroll
    for (int j = 1; j < 8; j++) if (s[j] > s[i0]) i0 = j;
    int i1 = (i0 == 0) ? 1 : 0;
#pragma unroll
    for (int j = 0; j < 8; j++) if (j != i0 && s[j] > s[i1]) i1 = j;
    float d  = expf((float)(s[i1] - s[i0]));
    float g0 = 1.f / (1.f + d);
    float g1 = d / (1.f + d);

    if (sl == 0) {
        packed[t] = make_float4(__int_as_float(i0), __int_as_float(i1), g0, g1);
        atomicAdd(&lcnt[i0], 1);   // LDS atomics only
        atomicAdd(&lcnt[i1], 1);
    }
    __syncthreads();
    if (tid < 8) blockcnt[blockIdx.x * 8 + tid] = lcnt[tid];
}

// ------ R2: exclusive scan blockcnt[512][8] -> blockoff + counts. 1 block, 8 waves ------
__global__ __launch_bounds__(512) void scan_kernel(const int* __restrict__ blockcnt,
                                                   int* __restrict__ blockoff,
                                                   int* __restrict__ counts) {
    int w = threadIdx.x >> 6;    // expert
    int lane = threadIdx.x & 63;
    int v[8]; int partial = 0;
#pragma unroll
    for (int i = 0; i < 8; i++) { v[i] = blockcnt[(lane * 8 + i) * 8 + w]; partial += v[i]; }
    int inc = partial;
#pragma unroll
    for (int d = 1; d < 64; d <<= 1) {
        int tt = __shfl_up(inc, d, 64);
        if (lane >= d) inc += tt;
    }
    int run = inc - partial;
#pragma unroll
    for (int i = 0; i < 8; i++) { blockoff[(lane * 8 + i) * 8 + w] = run; run += v[i]; }
    if (lane == 63) counts[w] = inc;
}

// ------ R3: scatter tokens into per-expert lists via ballot ranks (deterministic) ------
// 512 blocks x 64 threads: thread i -> token b*32 + (i>>1), pick (i&1)
__global__ void scatter_kernel(const float4* __restrict__ packed,
                               const int* __restrict__ blockoff,
                               int* __restrict__ tokenlist, float* __restrict__ gatelist) {
    int b = blockIdx.x, i = threadIdx.x;
    int t = b * 32 + (i >> 1), p = i & 1;
    float4 pk = packed[t];
    int   e = p ? __float_as_int(pk.y) : __float_as_int(pk.x);
    float g = p ? pk.w : pk.z;
    unsigned long long lt = (1ull << i) - 1ull;
    int slot = 0;
#pragma unroll
    for (int j = 0; j < 8; j++) {
        unsigned long long m = __ballot(e == j);
        if (e == j) slot = blockoff[b * 8 + j] + __popcll(m & lt);
    }
    tokenlist[e * T_TOK + slot] = t;
    gatelist [e * T_TOK + slot] = g;
}

// ---------------- m97-style 128x128 GEMM, BK=64, 4 waves, global_load_lds staging ----------------
template<int PASS>
__global__ __launch_bounds__(256) void moe_gemm(
    const u16* __restrict__ A, const u16* __restrict__ W,
    const float* __restrict__ bias,
    const int* __restrict__ counts,
    const int* __restrict__ tokenlist, const float* __restrict__ gatelist,
    u16* __restrict__ Hout, float* __restrict__ out)
{
    constexpr int N = (PASS == 1) ? 768 : 512;
    constexpr int K = (PASS == 1) ? 512 : 768;

    __shared__ __align__(16) char smem[32768];
    __shared__ int   tokrow[128];
    __shared__ float gaterow[128];
    __shared__ int   spo[9];

    int tid = threadIdx.x;
    int rt  = blockIdx.x % ROWT;
    int ct  = blockIdx.x / ROWT;
    int row0 = rt * 128;

    if (tid == 0) {
        int s = 0;
#pragma unroll
        for (int e = 0; e < NEXP; e++) { spo[e] = s; s += (counts[e] + 127) & ~127; }
        spo[NEXP] = s;
    }
    __syncthreads();
    if (row0 >= spo[8]) return;
    int e = 0;
    while (row0 >= spo[e + 1]) e++;
    int lr0 = row0 - spo[e];
    int cnt = counts[e];
    if (tid < 128) {
        int slot = lr0 + tid;
        int cl   = slot < cnt ? slot : cnt - 1;
        tokrow[tid]  = tokenlist[e * T_TOK + cl];
        gaterow[tid] = gatelist[e * T_TOK + cl];
    }
    __syncthreads();

    int n0 = ct * 128;
    char* As = smem;
    char* Bs = smem + 16384;

    const u16* aptr[4];
    const u16* bptr[4];
    const u16* wbase = W + (size_t)e * ((size_t)N * K);
#pragma unroll
    for (int iss = 0; iss < 4; iss++) {
        int chunk = iss * 256 + tid;
        int row   = chunk >> 3;
        int c16   = (chunk & 7) ^ (row & 7);
        if (PASS == 1)
            aptr[iss] = A + (size_t)tokrow[row] * K + c16 * 8;
        else
            aptr[iss] = A + (size_t)(row0 + row) * K + c16 * 8;
        bptr[iss] = wbase + (size_t)(n0 + row) * K + c16 * 8;
    }

    int lane = tid & 63, w = tid >> 6;
    int wr = w >> 1, wc = w & 1;
    int lr = lane & 15, hk = lane >> 4;

    f32x4 acc[4][4];
#pragma unroll
    for (int mi = 0; mi < 4; mi++)
#pragma unroll
        for (int ni = 0; ni < 4; ni++)
            acc[mi][ni] = (f32x4){0.f, 0.f, 0.f, 0.f};

    for (int kk = 0; kk < K; kk += 64) {
#pragma unroll
        for (int iss = 0; iss < 4; iss++) {
            gload16(aptr[iss] + kk, As + (iss * 256 + tid) * 16);
            gload16(bptr[iss] + kk, Bs + (iss * 256 + tid) * 16);
        }
        __syncthreads();
#pragma unroll
        for (int ks = 0; ks < 2; ks++) {
            bf16x8 af[4], bfr[4];
#pragma unroll
            for (int mi = 0; mi < 4; mi++) {
                int row = wr * 64 + mi * 16 + lr;
                af[mi] = *(const bf16x8*)(As + row * 128 + (((ks * 4 + hk) ^ (row & 7)) * 16));
            }
#pragma unroll
            for (int ni = 0; ni < 4; ni++) {
                int row = wc * 64 + ni * 16 + lr;
                bfr[ni] = *(const bf16x8*)(Bs + row * 128 + (((ks * 4 + hk) ^ (row & 7)) * 16));
            }
#pragma unroll
            for (int mi = 0; mi < 4; mi++)
#pragma unroll
                for (int ni = 0; ni < 4; ni++)
                    acc[mi][ni] = __builtin_amdgcn_mfma_f32_16x16x32_bf16(
                        af[mi], bfr[ni], acc[mi][ni], 0, 0, 0);
        }
        __syncthreads();
    }

    if (PASS == 1) {
#pragma unroll
        for (int ni = 0; ni < 4; ni++) {
            int lcol = wc * 64 + ni * 16 + lr;
            float bb = bias[e * N + n0 + lcol];
#pragma unroll
            for (int mi = 0; mi < 4; mi++) {
#pragma unroll
                for (int r = 0; r < 4; r++) {
                    int row = wr * 64 + mi * 16 + hk * 4 + r;
                    *(u16*)(smem + row * 256 + lcol * 2) = f2bf(gelu_exact(acc[mi][ni][r] + bb));
                }
            }
        }
        __syncthreads();
#pragma unroll
        for (int iss = 0; iss < 8; iss++) {
            int chunk = iss * 256 + tid;
            int row = chunk >> 4, c16 = chunk & 15;
            uint4 v = *(const uint4*)(smem + row * 256 + c16 * 16);
            *(uint4*)(Hout + (size_t)(row0 + row) * 768 + n0 + c16 * 8) = v;
        }
    } else {
#pragma unroll
        for (int ni = 0; ni < 4; ni++) {
            int gcol = n0 + wc * 64 + ni * 16 + lr;
            float bb = bias[e * N + gcol];
#pragma unroll
            for (int mi = 0; mi < 4; mi++) {
#pragma unroll
                for (int r = 0; r < 4; r++) {
                    int row  = wr * 64 + mi * 16 + hk * 4 + r;
                    int slot = lr0 + row;
                    if (slot < cnt) {
                        int   tok = tokrow[row];
                        float g   = gaterow[row];
                        atomicAdd(out + (size_t)tok * 512 + gcol,
                                  (acc[mi][ni][r] + bb) * g);
                    }
                }
            }
        }
    }
}

extern "C" void kernel_launch(void* const* d_in, const int* in_sizes, int n_in,
                              void* d_out, int out_size, void* d_ws, size_t ws_size,
                              hipStream_t stream) {
    const float* x  = (const float*)d_in[0];   // [8,2048,512]
    const float* Wg = (const float*)d_in[1];   // [512,8]
    const float* bg = (const float*)d_in[2];   // [8]
    const float* W1 = (const float*)d_in[3];   // [8,512,768]
    const float* b1 = (const float*)d_in[4];   // [8,768]
    const float* W2 = (const float*)d_in[5];   // [8,768,512]
    const float* b2 = (const float*)d_in[6];   // [8,512]
    float* out = (float*)d_out;                // [8,2048,512] fp32

    char* ws = (char*)d_ws;
    int*    counts    = (int*)(ws + 0);                   // 8 int
    int*    blockcnt  = (int*)(ws + 1024);                // 512*8 int (16 KB)
    int*    blockoff  = (int*)(ws + 17408);               // 512*8 int (16 KB)
    float4* packed    = (float4*)(ws + 33792);            // 16384*16 B (256 KB)
    int*    tokenlist = (int*)(ws + 295936);              // 8*16384 int (512 KB)
    float*  gatelist  = (float*)(ws + 820224);            // 8*16384 f32 (512 KB)
    u16*    xb        = (u16*)(ws + 1344512);             // 16 MB
    u16*    W1t       = (u16*)(ws + 18121728);            // 6 MB
    u16*    W2t       = (u16*)(ws + 24413184);            // 6 MB
    u16*    H         = (u16*)(ws + 30704640);            // 51.9 MB
    (void)in_sizes; (void)n_in; (void)ws_size;

    hipMemsetAsync(d_out, 0, (size_t)out_size * sizeof(float), stream);

    router_kernel<<<512, 256, 0, stream>>>(x, Wg, bg, xb, packed, blockcnt);
    transpose_all_kernel<<<6144, 256, 0, stream>>>(W1, W2, W1t, W2t);
    scan_kernel<<<1, 512, 0, stream>>>(blockcnt, blockoff, counts);
    scatter_kernel<<<512, 64, 0, stream>>>(packed, blockoff, tokenlist, gatelist);

    moe_gemm<1><<<6 * ROWT, 256, 0, stream>>>(xb, W1t, b1, counts,
                                              tokenlist, gatelist, H, nullptr);
    moe_gemm<2><<<4 * ROWT, 256, 0, stream>>>(H, W2t, b2, counts,
                                              tokenlist, gatelist, nullptr, out);
}

// Round 7
// 269.254 us; speedup vs baseline: 2.0783x; 1.1411x over previous
//
#include <hip/hip_runtime.h>
#include <math.h>
#include <stdint.h>

typedef unsigned short u16;
typedef unsigned int u32;
typedef __attribute__((ext_vector_type(8))) short bf16x8;   // 8 bf16 (4 VGPRs)
typedef __attribute__((ext_vector_type(4))) float f32x4;    // MFMA C/D

#define T_TOK 16384
#define NEXP 8

__device__ __forceinline__ u16 f2bf(float f) {
    union { float f; unsigned u; } v; v.f = f;
    unsigned u = v.u;
    return (u16)((u + 0x7fffu + ((u >> 16) & 1u)) >> 16);   // RNE
}

// exact-GELU via Abramowitz-Stegun 7.1.26 erf (max abs err 1.5e-7 << bf16 ulp)
__device__ __forceinline__ float gelu_exact(float h) {
    float x  = h * 0.70710678118654752f;
    float ax = fabsf(x);
    float t  = __builtin_amdgcn_rcpf(1.f + 0.3275911f * ax);
    float p  = t * (0.254829592f + t * (-0.284496736f + t * (1.421413741f +
               t * (-1.453152027f + t * 1.061405429f))));
    float er = 1.f - p * __expf(-x * x);
    er = (x < 0.f) ? -er : er;
    return 0.5f * h * (1.f + er);
}

// async global->LDS, 16B per lane. LDS dest must be wave-uniform base + lane*16.
__device__ __forceinline__ void gload16(const void* g, void* l) {
    __builtin_amdgcn_global_load_lds(
        (const __attribute__((address_space(1))) u32*)(unsigned long long)(uintptr_t)g,
        (__attribute__((address_space(3))) u32*)(unsigned int)(uintptr_t)l,
        16, 0, 0);
}

__device__ __forceinline__ double shfl_xor_dbl(double v, int m) {
    union { double d; int i[2]; } u; u.d = v;
    u.i[0] = __shfl_xor(u.i[0], m, 64);
    u.i[1] = __shfl_xor(u.i[1], m, 64);
    return u.d;
}

// ---- weights -> MFMA fragment layout, bf16 ----
// input viewed as [e][K][N] f32 (W1: K=512 d_in, N=768 hidden; W2: K=768, N=512).
// output frag f = nf*(K/32)+kf: u16 at ((f*64 + lane)*8 + j) holds
// element (col = nf*16 + (lane&15), k = kf*32 + (lane>>4)*8 + j)  [MFMA B-operand order]
__global__ __launch_bounds__(256) void wfrag_kernel(
    const float* __restrict__ W1, const float* __restrict__ W2,
    u16* __restrict__ W1f, u16* __restrict__ W2f) {
    __shared__ float tile[32][65];
    int id = blockIdx.x;
    const float* src; u16* dst; int K, N, e, k0, n0;
    if (id < 1536) {            // 8e x 16kf x 12ngrp
        K = 512; N = 768; e = id / 192; int rem = id % 192;
        k0 = (rem / 12) * 32; n0 = (rem % 12) * 64;
        src = W1; dst = W1f;
    } else {                    // 8e x 24kf x 8ngrp
        id -= 1536;
        K = 768; N = 512; e = id / 192; int rem = id % 192;
        k0 = (rem / 8) * 32; n0 = (rem % 8) * 64;
        src = W2; dst = W2f;
    }
    int tid = threadIdx.x;
    const float* s = src + (size_t)e * K * N + (size_t)k0 * N + n0;
#pragma unroll
    for (int it = 0; it < 8; it++) {
        int idx = it * 256 + tid;
        int kk = idx >> 6, nn = idx & 63;
        tile[kk][nn] = s[(size_t)kk * N + nn];
    }
    __syncthreads();
    int w = tid >> 6, lane = tid & 63;
    int c = w * 16 + (lane & 15), ksub = (lane >> 4) * 8;
    union { u16 a[8]; uint4 v; } o;
#pragma unroll
    for (int j = 0; j < 8; j++) o.a[j] = f2bf(tile[ksub + j][c]);
    int KF = K >> 5;
    int nf = (n0 >> 4) + w, kf = k0 >> 5;
    *(uint4*)(dst + (size_t)e * 393216 + ((size_t)(nf * KF + kf) * 64 + lane) * 8) = o.v;
}

// ------ R1: routing math (fp64), emits xb (bf16 x), packed choices, per-block counts ------
__global__ __launch_bounds__(256) void router_kernel(
    const float* __restrict__ x, const float* __restrict__ Wg,
    const float* __restrict__ bg,
    u16* __restrict__ xb, float4* __restrict__ packed, int* __restrict__ blockcnt) {
    __shared__ double wgd[4096];
    __shared__ int lcnt[8];
    int tid = threadIdx.x;
    if (tid < 8) lcnt[tid] = 0;
    for (int i = tid; i < 4096; i += 256) {
        int k = i >> 3, j = i & 7;
        int slot = (j + ((k >> 2) & 7)) & 7;
        wgd[k * 8 + slot] = (double)Wg[i];
    }
    __syncthreads();

    int w = tid >> 6, lane = tid & 63;
    int tg = lane >> 3, sl = lane & 7;
    int t  = blockIdx.x * 32 + w * 8 + tg;
    const float* xr = x  + (size_t)t * 512;
    u16*       xrow = xb + (size_t)t * 512;

    float4 xv[16];
#pragma unroll
    for (int it = 0; it < 16; it++)
        xv[it] = *(const float4*)(xr + it * 32 + sl * 4);

#pragma unroll
    for (int it = 0; it < 16; it++) {
        ushort4 o;
        o.x = f2bf(xv[it].x); o.y = f2bf(xv[it].y);
        o.z = f2bf(xv[it].z); o.w = f2bf(xv[it].w);
        *(ushort4*)(xrow + it * 32 + sl * 4) = o;
    }

    int jr[8];
#pragma unroll
    for (int j = 0; j < 8; j++) jr[j] = (j + sl) & 7;

    double acc[8];
#pragma unroll
    for (int j = 0; j < 8; j++) acc[j] = 0.0;
#pragma unroll
    for (int it = 0; it < 16; it++) {
        float vv[4] = { xv[it].x, xv[it].y, xv[it].z, xv[it].w };
#pragma unroll
        for (int q = 0; q < 4; q++) {
            int k = it * 32 + sl * 4 + q;
            double dv = (double)vv[q];
            const double* wr = wgd + (size_t)k * 8;
#pragma unroll
            for (int j = 0; j < 8; j++)
                acc[j] += dv * wr[jr[j]];
        }
    }
#pragma unroll
    for (int j = 0; j < 8; j++) {
        acc[j] += shfl_xor_dbl(acc[j], 1);
        acc[j] += shfl_xor_dbl(acc[j], 2);
        acc[j] += shfl_xor_dbl(acc[j], 4);
    }

    double s[8];
#pragma unroll
    for (int j = 0; j < 8; j++) s[j] = acc[j] + (double)bg[j];
    int i0 = 0;
#pragma unroll
    for (int j = 1; j < 8; j++) if (s[j] > s[i0]) i0 = j;
    int i1 = (i0 == 0) ? 1 : 0;
#pragma unroll
    for (int j = 0; j < 8; j++) if (j != i0 && s[j] > s[i1]) i1 = j;
    float d  = expf((float)(s[i1] - s[i0]));
    float g0 = 1.f / (1.f + d);
    float g1 = d / (1.f + d);

    if (sl == 0) {
        packed[t] = make_float4(__int_as_float(i0), __int_as_float(i1), g0, g1);
        atomicAdd(&lcnt[i0], 1);   // LDS atomics only
        atomicAdd(&lcnt[i1], 1);
    }
    __syncthreads();
    if (tid < 8) blockcnt[blockIdx.x * 8 + tid] = lcnt[tid];
}

// ------ R2: exclusive scan blockcnt[512][8] -> blockoff + counts ------
__global__ __launch_bounds__(512) void scan_kernel(const int* __restrict__ blockcnt,
                                                   int* __restrict__ blockoff,
                                                   int* __restrict__ counts) {
    int w = threadIdx.x >> 6;    // expert
    int lane = threadIdx.x & 63;
    int v[8]; int partial = 0;
#pragma unroll
    for (int i = 0; i < 8; i++) { v[i] = blockcnt[(lane * 8 + i) * 8 + w]; partial += v[i]; }
    int inc = partial;
#pragma unroll
    for (int d = 1; d < 64; d <<= 1) {
        int tt = __shfl_up(inc, d, 64);
        if (lane >= d) inc += tt;
    }
    int run = inc - partial;
#pragma unroll
    for (int i = 0; i < 8; i++) { blockoff[(lane * 8 + i) * 8 + w] = run; run += v[i]; }
    if (lane == 63) counts[w] = inc;
}

// ------ R3: scatter tokens into per-expert lists via ballot ranks ------
__global__ void scatter_kernel(const float4* __restrict__ packed,
                               const int* __restrict__ blockoff,
                               int* __restrict__ tokenlist, float* __restrict__ gatelist) {
    int b = blockIdx.x, i = threadIdx.x;
    int t = b * 32 + (i >> 1), p = i & 1;
    float4 pk = packed[t];
    int   e = p ? __float_as_int(pk.y) : __float_as_int(pk.x);
    float g = p ? pk.w : pk.z;
    unsigned long long lt = (1ull << i) - 1ull;
    int slot = 0;
#pragma unroll
    for (int j = 0; j < 8; j++) {
        unsigned long long m = __ballot(e == j);
        if (e == j) slot = blockoff[b * 8 + j] + __popcll(m & lt);
    }
    tokenlist[e * T_TOK + slot] = t;
    gatelist [e * T_TOK + slot] = g;
}

// ---------------- fused expert MLP: 64 tokens/block, 8 waves, weights streamed as frags ----------------
// expert = blockIdx&7 -> XCD-affine L2 residency of that expert's 1.5MB weights.
// GEMM1: H[64][768] = GELU(X@W1+b1), X staged in 2 LDS K-halves (only barriers), B direct frags.
// GEMM2: O[64][512] = H@W2, H read from swizzled LDS, B direct frags; gated atomic scatter.
__global__ __launch_bounds__(512, 2) void fused_expert_kernel(
    const u16* __restrict__ xb, const u16* __restrict__ W1f, const u16* __restrict__ W2f,
    const float* __restrict__ b1, const float* __restrict__ b2,
    const int* __restrict__ counts, const int* __restrict__ tokenlist,
    const float* __restrict__ gatelist, float* __restrict__ out)
{
    int e = blockIdx.x & 7;
    int g = blockIdx.x >> 3;
    int cnt = counts[e];
    int row0 = g * 64;
    if (row0 >= cnt) return;

    __shared__ __align__(16) char smem[131840];
    char* Xl = smem;                  // [64][256] bf16 (K-half), swizzled, 32 KB
    char* Hl = smem + 32768;          // [64][768] bf16, swizzled, 96 KB
    int*   tokrow  = (int*)(smem + 131072);
    float* gaterow = (float*)(smem + 131328);

    int tid = threadIdx.x;
    if (tid < 64) {
        int slot = row0 + tid;
        int cl = slot < cnt ? slot : cnt - 1;
        tokrow[tid]  = tokenlist[e * T_TOK + cl];
        gaterow[tid] = gatelist[e * T_TOK + cl];
    }
    __syncthreads();

    int lane = tid & 63, w = tid >> 6;
    int lr = lane & 15, hk = lane >> 4;

    // staging srcs: dest chunk linear, source chunk pre-swizzled (involution with reads)
    const u16* aptr[4];
#pragma unroll
    for (int i = 0; i < 4; i++) {
        int chunk = i * 512 + tid;
        int row = chunk >> 5, c = chunk & 31;
        int csrc = (c & 24) | ((c & 7) ^ (row & 7));
        aptr[i] = xb + (size_t)tokrow[row] * 512 + csrc * 8;
    }

    const u16* w1b = W1f + (size_t)e * 393216;
    const u16* w2b = W2f + (size_t)e * 393216;

    f32x4 acc1[4][6];
#pragma unroll
    for (int mi = 0; mi < 4; mi++)
#pragma unroll
        for (int ni = 0; ni < 6; ni++)
            acc1[mi][ni] = (f32x4){0.f, 0.f, 0.f, 0.f};

#pragma unroll
    for (int h = 0; h < 2; h++) {
        if (h) __syncthreads();                   // all waves done reading half 0
#pragma unroll
        for (int i = 0; i < 4; i++)
            gload16(aptr[i] + h * 256, Xl + (i * 512 + tid) * 16);
        __syncthreads();                          // staging complete
#pragma unroll
        for (int ks = 0; ks < 8; ks++) {
            bf16x8 a[4], b[6];
#pragma unroll
            for (int mi = 0; mi < 4; mi++) {
                int row = mi * 16 + lr;
                int chunk = ks * 4 + hk;
                int sw = (chunk & 24) | ((chunk & 7) ^ (row & 7));
                a[mi] = *(const bf16x8*)(Xl + row * 512 + sw * 16);
            }
            int kf = h * 8 + ks;
#pragma unroll
            for (int ni = 0; ni < 6; ni++) {
                int nf = w * 6 + ni;
                b[ni] = *(const bf16x8*)(w1b + ((nf * 16 + kf) * 64 + lane) * 8);
            }
#pragma unroll
            for (int mi = 0; mi < 4; mi++)
#pragma unroll
                for (int ni = 0; ni < 6; ni++)
                    acc1[mi][ni] = __builtin_amdgcn_mfma_f32_16x16x32_bf16(
                        a[mi], b[ni], acc1[mi][ni], 0, 0, 0);
        }
    }

    // bias + GELU -> H LDS (swizzled)
    float b1v[6];
#pragma unroll
    for (int ni = 0; ni < 6; ni++) b1v[ni] = b1[e * 768 + w * 96 + ni * 16 + lr];
#pragma unroll
    for (int ni = 0; ni < 6; ni++) {
        int col = w * 96 + ni * 16 + lr;
        int cb = col >> 3;                 // 16B chunk index within row
        int lo = (col * 2) & 15;
#pragma unroll
        for (int mi = 0; mi < 4; mi++) {
#pragma unroll
            for (int r = 0; r < 4; r++) {
                int row = mi * 16 + hk * 4 + r;
                int sw = (cb & ~7) | ((cb & 7) ^ (row & 7));
                *(u16*)(Hl + row * 1536 + sw * 16 + lo) =
                    f2bf(gelu_exact(acc1[mi][ni][r] + b1v[ni]));
            }
        }
    }
    __syncthreads();

    f32x4 acc2[4][4];
#pragma unroll
    for (int mi = 0; mi < 4; mi++)
#pragma unroll
        for (int ni = 0; ni < 4; ni++)
            acc2[mi][ni] = (f32x4){0.f, 0.f, 0.f, 0.f};

#pragma unroll
    for (int ks = 0; ks < 24; ks++) {
        bf16x8 a[4], b[4];
#pragma unroll
        for (int mi = 0; mi < 4; mi++) {
            int row = mi * 16 + lr;
            int chunk = ks * 4 + hk;
            int sw = (chunk & ~7) | ((chunk & 7) ^ (row & 7));
            a[mi] = *(const bf16x8*)(Hl + row * 1536 + sw * 16);
        }
#pragma unroll
        for (int ni = 0; ni < 4; ni++) {
            int nf = w * 4 + ni;
            b[ni] = *(const bf16x8*)(w2b + ((nf * 24 + ks) * 64 + lane) * 8);
        }
#pragma unroll
        for (int mi = 0; mi < 4; mi++)
#pragma unroll
            for (int ni = 0; ni < 4; ni++)
                acc2[mi][ni] = __builtin_amdgcn_mfma_f32_16x16x32_bf16(
                    a[mi], b[ni], acc2[mi][ni], 0, 0, 0);
    }

    // epilogue: out[token] += gate * (O + b2)
    float b2v[4];
#pragma unroll
    for (int ni = 0; ni < 4; ni++) b2v[ni] = b2[e * 512 + w * 64 + ni * 16 + lr];
#pragma unroll
    for (int mi = 0; mi < 4; mi++) {
#pragma unroll
        for (int r = 0; r < 4; r++) {
            int row  = mi * 16 + hk * 4 + r;
            int slot = row0 + row;
            if (slot < cnt) {
                int   tok = tokrow[row];
                float gg  = gaterow[row];
                float* orow = out + (size_t)tok * 512 + w * 64 + lr;
#pragma unroll
                for (int ni = 0; ni < 4; ni++)
                    atomicAdd(orow + ni * 16, (acc2[mi][ni][r] + b2v[ni]) * gg);
            }
        }
    }
}

extern "C" void kernel_launch(void* const* d_in, const int* in_sizes, int n_in,
                              void* d_out, int out_size, void* d_ws, size_t ws_size,
                              hipStream_t stream) {
    const float* x  = (const float*)d_in[0];   // [8,2048,512]
    const float* Wg = (const float*)d_in[1];   // [512,8]
    const float* bg = (const float*)d_in[2];   // [8]
    const float* W1 = (const float*)d_in[3];   // [8,512,768]
    const float* b1 = (const float*)d_in[4];   // [8,768]
    const float* W2 = (const float*)d_in[5];   // [8,768,512]
    const float* b2 = (const float*)d_in[6];   // [8,512]
    float* out = (float*)d_out;                // [8,2048,512] fp32

    char* ws = (char*)d_ws;
    int*    counts    = (int*)(ws + 0);                   // 8 int
    int*    blockcnt  = (int*)(ws + 1024);                // 512*8 int
    int*    blockoff  = (int*)(ws + 17408);               // 512*8 int
    float4* packed    = (float4*)(ws + 33792);            // 16384*16 B
    int*    tokenlist = (int*)(ws + 295936);              // 8*16384 int
    float*  gatelist  = (float*)(ws + 820224);            // 8*16384 f32
    u16*    xb        = (u16*)(ws + 1344512);             // 16 MB
    u16*    W1f       = (u16*)(ws + 18121728);            // 6 MB frag-layout
    u16*    W2f       = (u16*)(ws + 24413184);            // 6 MB frag-layout
    (void)in_sizes; (void)n_in; (void)ws_size;

    hipMemsetAsync(d_out, 0, (size_t)out_size * sizeof(float), stream);

    router_kernel<<<512, 256, 0, stream>>>(x, Wg, bg, xb, packed, blockcnt);
    wfrag_kernel<<<3072, 256, 0, stream>>>(W1, W2, W1f, W2f);
    scan_kernel<<<1, 512, 0, stream>>>(blockcnt, blockoff, counts);
    scatter_kernel<<<512, 64, 0, stream>>>(packed, blockoff, tokenlist, gatelist);

    fused_expert_kernel<<<2048, 512, 0, stream>>>(xb, W1f, W2f, b1, b2,
                                                  counts, tokenlist, gatelist, out);
}